// Round 14
// baseline (566.864 us; speedup 1.0000x reference)
//
#include <hip/hip_runtime.h>
#include <hip/hip_bf16.h>

typedef unsigned short u16;
typedef unsigned int u32;
typedef __attribute__((ext_vector_type(8))) short bf16x8;
typedef __attribute__((ext_vector_type(4))) float f32x4;
typedef __attribute__((ext_vector_type(2))) float f32x2;

#define NB   1024
#define LMI  30
#define LTG  50
#define NN   80
#define ROWS (NB*NN)      // 81920
#define FF   512
#define HH   4
#define CC   128

// ---------- helpers ----------
__device__ __forceinline__ u16 f2b(float f) {
    u32 u = __float_as_uint(f);
    u32 r = (u + 0x7FFFu + ((u >> 16) & 1u)) >> 16;
    return (u16)r;
}
__device__ __forceinline__ float b2f(u16 h) {
    return __uint_as_float(((u32)h) << 16);
}
__device__ __forceinline__ float gelu_f(float v) {
    return 0.5f * v * (1.0f + erff(v * 0.70710678118654752440f));
}
// unpack 2 packed bf16 (one u32) -> 2 f32
__device__ __forceinline__ f32x2 bfp2f(u32 p) {
    f32x2 r;
    r.x = __uint_as_float(p << 16);
    r.y = __uint_as_float(p & 0xffff0000u);
    return r;
}
__device__ __forceinline__ f32x2 vmax2(f32x2 a, f32x2 b) {
#if __has_builtin(__builtin_elementwise_max)
    return __builtin_elementwise_max(a, b);
#else
    f32x2 r; r.x = fmaxf(a.x, b.x); r.y = fmaxf(a.y, b.y); return r;
#endif
}
// async global->LDS, 16B per lane; LDS dest is wave-uniform base + lane*16
__device__ __forceinline__ void gload_lds16(const void* g, void* l) {
    __builtin_amdgcn_global_load_lds(
        (__attribute__((address_space(1))) void*)(uintptr_t)g,
        (__attribute__((address_space(3))) void*)(uintptr_t)l,
        16, 0, 0);
}

// ---------- workspace layout (bytes) ----------
#define X_OFF     0ULL
#define XLR_OFF   83886080ULL                 // x: 81920*512*2
#define INWT_OFF  251658240ULL                // xlr: 81920*1024*2
#define WLRT_OFF  (INWT_OFF + 262144ULL)
#define BIAS_OFF  (WLRT_OFF + 2097152ULL)
#define EER_OFF   (BIAS_OFF + 8192ULL)
#define EES_OFF   (EER_OFF + 8192ULL)
// total ws needed = EES_OFF + 327680 = 254,361,600 B

// ---------- prep: weight transpose/convert + edge tables (r10-proven) ----------
__global__ __launch_bounds__(256)
void prep_misc(const float* __restrict__ in_W, const float* __restrict__ gat_Wl,
               const float* __restrict__ gat_bl, const float* __restrict__ gat_Wr,
               const float* __restrict__ gat_br, const float* __restrict__ gat_We,
               const float* __restrict__ eemb,
               u16* __restrict__ inWt, u16* __restrict__ Wlrt,
               float* __restrict__ biaslr, float* __restrict__ eereal,
               float* __restrict__ eeself)
{
    int idx = blockIdx.x * 256 + threadIdx.x;
    if (idx < 131072) {
        int n = idx >> 8, k = idx & 255;
        inWt[idx] = f2b(in_W[k * 512 + n]);
        return;
    }
    idx -= 131072;
    if (idx < 1048576) {
        int l = idx >> 19; int r = idx & 524287; int n = r >> 9, k = r & 511;
        float v = (n < 512) ? gat_Wl[(size_t)l * 262144 + (size_t)k * 512 + n]
                            : gat_Wr[(size_t)l * 262144 + (size_t)k * 512 + (n - 512)];
        Wlrt[idx] = f2b(v);
        return;
    }
    idx -= 1048576;
    if (idx < 2048) {
        int l = idx >> 10, n = idx & 1023;
        biaslr[idx] = (n < 512) ? gat_bl[l * 512 + n] : gat_br[l * 512 + (n - 512)];
        return;
    }
    idx -= 2048;
    if (idx < 2048) {
        int l = idx >> 10; int r = idx & 1023; int t = r >> 9, f = r & 511;
        int et = t ? 2 : 0;
        float v = 0.f;
        #pragma unroll
        for (int h = 0; h < 4; ++h)
            v += eemb[et * 4 + h] * gat_We[l * 2048 + h * 512 + f];
        eereal[idx] = v;
        return;
    }
    idx -= 2048;
    if (idx < 81920) {
        int l = idx / 40960; int r = idx % 40960; int n = r >> 9, f = r & 511;
        int LL = (n < LMI) ? LMI : LTG;
        int p  = (n < LMI) ? n : (n - LMI);
        float c1 = (float)((p >= 1) + (p <= LL - 2));
        float c2 = (float)((p >= 2) + (p <= LL - 3));
        float ic = 1.0f / (c1 + c2);
        float v = 0.f;
        #pragma unroll
        for (int h = 0; h < 4; ++h) {
            float attr = (c1 * eemb[0 * 4 + h] + c2 * eemb[2 * 4 + h]) * ic;
            v += attr * gat_We[l * 2048 + h * 512 + f];
        }
        eeself[idx] = v;
        return;
    }
}

// ---------- prep: build xin (input + node-type emb) in bf16, 4 nodes/block ----------
__global__ __launch_bounds__(256)
void prep_xin(const float* __restrict__ mirna, const float* __restrict__ target,
              const float* __restrict__ nte, u16* __restrict__ xin)
{
    int bid = blockIdx.x * 4 + (threadIdx.x >> 6);   // b*80+n
    int b = bid / NN, n = bid % NN;
    int t = threadIdx.x & 63;
    const float* src; const float* tv;
    if (n < LMI) { src = mirna + ((size_t)b * LMI + n) * 256; tv = nte; }
    else         { src = target + ((size_t)b * LTG + (n - LMI)) * 256; tv = nte + 256; }
    float4 v = *(const float4*)(src + t * 4);
    float4 e = *(const float4*)(tv + t * 4);
    u32 p0 = (u32)f2b(v.x + e.x) | ((u32)f2b(v.y + e.y) << 16);
    u32 p1 = (u32)f2b(v.z + e.z) | ((u32)f2b(v.w + e.w) << 16);
    *(uint2*)(xin + (size_t)bid * 256 + t * 4) = make_uint2(p0, p1);
}

// ---------- GEMM (r12-proven best: 110us layer): 256x256 tile, 16 waves,
// wave tile 64x64, BK=64, 2 LDS buffers, STAGE-first + one vmcnt(0)+barrier
// at step end, XOR kslot staging (0 conflicts), XCD swizzle, 8B epilogue ----
template<int N, int K>
__global__ __launch_bounds__(1024, 1)
void gemm_nt_bias(const u16* __restrict__ A, const u16* __restrict__ Bt,
                  const float* __restrict__ bias, u16* __restrict__ Cout)
{
    __shared__ __align__(16) u16 sm[2][4][8192];   // 128 KiB
    const int tid = threadIdx.x;
    const int w = tid >> 6, l = tid & 63;   // w: 0..15
    constexpr int ncb = N / 256;
    constexpr int nsteps = K >> 6;

    const int per = gridDim.x >> 3;
    const int nid = (blockIdx.x & 7) * per + (blockIdx.x >> 3);
    const int row0 = (nid / ncb) * 256;
    const int col0 = (nid % ncb) * 256;
    const int wr = w >> 2, wc = w & 3;      // wave tile rows [wr*64,+64), cols [wc*64,+64)

    const int srow = l >> 2;
    const int kperm = ((l & 3) ^ ((l >> 3) & 3)) * 8;
    const u16* Ag = A  + (size_t)(row0 + w * 16 + srow) * K + kperm;
    const u16* Bg = Bt + (size_t)(col0 + w * 16 + srow) * K + kperm;

#define STAGE(buf, t) do { int _ko = (t) << 6;                  \
        gload_lds16(Ag + _ko,      &sm[buf][0][w * 512]);       \
        gload_lds16(Ag + _ko + 32, &sm[buf][1][w * 512]);       \
        gload_lds16(Bg + _ko,      &sm[buf][2][w * 512]);       \
        gload_lds16(Bg + _ko + 32, &sm[buf][3][w * 512]);       \
    } while (0)

    f32x4 acc[4][4];
    #pragma unroll
    for (int r = 0; r < 4; ++r)
        #pragma unroll
        for (int f = 0; f < 4; ++f)
            acc[r][f] = (f32x4){0.f, 0.f, 0.f, 0.f};

    const int ll = l & 15, lh = l >> 4;
    const int aoff = ll * 32 + ((lh ^ ((ll >> 1) & 3)) * 8);
    const int aB = wr * 4 * 512 + aoff;
    const int bB = wc * 4 * 512 + aoff;

    STAGE(0, 0);
    asm volatile("s_waitcnt vmcnt(0)" ::: "memory");
    __builtin_amdgcn_s_barrier();

    #pragma unroll
    for (int t = 0; t < nsteps; ++t) {
        const int cur = t & 1;
        if (t + 1 < nsteps) STAGE(cur ^ 1, t + 1);

        #pragma unroll
        for (int kh = 0; kh < 2; ++kh) {
            bf16x8 af[4], bfr[4];
            #pragma unroll
            for (int ar = 0; ar < 4; ++ar)
                af[ar] = *(const bf16x8*)&sm[cur][kh][aB + ar * 512];
            #pragma unroll
            for (int fc = 0; fc < 4; ++fc)
                bfr[fc] = *(const bf16x8*)&sm[cur][2 + kh][bB + fc * 512];
            __builtin_amdgcn_s_setprio(1);
            #pragma unroll
            for (int ar = 0; ar < 4; ++ar)
                #pragma unroll
                for (int fc = 0; fc < 4; ++fc)
                    acc[ar][fc] = __builtin_amdgcn_mfma_f32_16x16x32_bf16(
                        bfr[fc], af[ar], acc[ar][fc], 0, 0, 0);
            __builtin_amdgcn_s_setprio(0);
        }

        if (t + 1 < nsteps) {
            asm volatile("s_waitcnt vmcnt(0)" ::: "memory");
            __builtin_amdgcn_s_barrier();
        }
    }
#undef STAGE

    #pragma unroll
    for (int ar = 0; ar < 4; ++ar) {
        int grow = row0 + wr * 64 + ar * 16 + ll;
        #pragma unroll
        for (int fc = 0; fc < 4; ++fc) {
            int n0 = col0 + wc * 64 + fc * 16 + lh * 4;
            float4 bv = *(const float4*)(bias + n0);
            u32 lo = (u32)f2b(acc[ar][fc][0] + bv.x) | ((u32)f2b(acc[ar][fc][1] + bv.y) << 16);
            u32 hi = (u32)f2b(acc[ar][fc][2] + bv.z) | ((u32)f2b(acc[ar][fc][3] + bv.w) << 16);
            *(uint2*)&Cout[(size_t)grow * N + n0] = make_uint2(lo, hi);
        }
    }
}

// ---------- row LN + gelu: 4 rows/block, wave per row, 8 ch/lane ----------
__global__ __launch_bounds__(256)
void ln_gelu_rows(u16* __restrict__ x, const float* __restrict__ g, const float* __restrict__ b)
{
    int w = threadIdx.x >> 6, l = threadIdx.x & 63;
    size_t row = (size_t)blockIdx.x * 4 + w;
    u16* rp = x + row * FF + l * 8;
    bf16x8 v = *(const bf16x8*)rp;
    float y[8]; float s = 0.f, q = 0.f;
    #pragma unroll
    for (int j = 0; j < 8; ++j) { y[j] = b2f((u16)v[j]); s += y[j]; q += y[j] * y[j]; }
    #pragma unroll
    for (int st = 32; st; st >>= 1) { s += __shfl_xor(s, st, 64); q += __shfl_xor(q, st, 64); }
    float mu = s * (1.0f / 512.0f);
    float var = q * (1.0f / 512.0f) - mu * mu;
    float rs = rsqrtf(var + 1e-5f);
    float4 g0 = *(const float4*)(g + l * 8), g1 = *(const float4*)(g + l * 8 + 4);
    float4 b0 = *(const float4*)(b + l * 8), b1 = *(const float4*)(b + l * 8 + 4);
    float gv[8] = {g0.x, g0.y, g0.z, g0.w, g1.x, g1.y, g1.z, g1.w};
    float bv[8] = {b0.x, b0.y, b0.z, b0.w, b1.x, b1.y, b1.z, b1.w};
    bf16x8 o;
    #pragma unroll
    for (int j = 0; j < 8; ++j) {
        float z = (y[j] - mu) * rs * gv[j] + bv[j];
        o[j] = (short)f2b(gelu_f(z));
    }
    *(bf16x8*)rp = o;
}

// ---------- fused GAT layer: 4 nodes/block, wave=head, 16 lanes/node ----------
// Packed-f32 (v_pk_*) inner math: all per-channel edge/PV ops on f32x2.
__global__ __launch_bounds__(256)
void gat_layer(u16* __restrict__ x, const u16* __restrict__ xlr,
               const float* __restrict__ att, const float* __restrict__ eereal,
               const float* __restrict__ eeself, const float* __restrict__ bo,
               const float* __restrict__ g, const float* __restrict__ bta,
               int apply_gelu)
{
    int tid = threadIdx.x;
    int h = tid >> 6, l = tid & 63;
    int s = l >> 4, t = l & 15;
    int row = blockIdx.x * 4 + s;        // global node row
    int n = row % NN;
    int lo = (n < LMI) ? 0 : LMI;
    int hi = (n < LMI) ? (LMI - 1) : (NN - 1);
    int c = h * CC + t * 8;              // 8 channels [c, c+8)

    // own xr (packed), att (packed)
    bf16x8 xrv = *(const bf16x8*)(xlr + (size_t)row * 1024 + 512 + c);
    const u32* xru = (const u32*)&xrv;
    f32x2 xr2[4], att2[4];
    #pragma unroll
    for (int jj = 0; jj < 4; ++jj) {
        xr2[jj]  = bfp2f(xru[jj]);
        att2[jj] = ((const f32x2*)(att + c))[jj];
    }

    // xre2[sel][jj] = xr + edge-attr (sel 0: d=+-1, 1: d=+-2, 2: self)
    f32x2 xre2[3][4];
    {
        const f32x2* e0p = (const f32x2*)(eereal + c);
        const f32x2* e1p = (const f32x2*)(eereal + 512 + c);
        const f32x2* e2p = (const f32x2*)(eeself + (size_t)n * 512 + c);
        #pragma unroll
        for (int jj = 0; jj < 4; ++jj) {
            xre2[0][jj] = xr2[jj] + e0p[jj];
            xre2[1][jj] = xr2[jj] + e1p[jj];
            xre2[2][jj] = xr2[jj] + e2p[jj];
        }
    }

    f32x2 vf2[5][4];
    float p5[5];
    float amax = -1e30f;
    #pragma unroll
    for (int i = 0; i < 5; ++i) {
        int d = i - 2;
        int src = n + d;
        bool ok = (src >= lo) && (src <= hi);
        int dd = ok ? d : 0;
        bf16x8 vv = *(const bf16x8*)(xlr + (size_t)(row + dd) * 1024 + c);
        const u32* vu = (const u32*)&vv;
        const int sel = (i == 2) ? 2 : ((i == 1 || i == 3) ? 0 : 1);
        f32x2 p2 = {0.f, 0.f};
        #pragma unroll
        for (int jj = 0; jj < 4; ++jj) {
            f32x2 v2 = bfp2f(vu[jj]);
            vf2[i][jj] = v2;
            f32x2 m2 = v2 + xre2[sel][jj];
            f32x2 lk = vmax2(m2, m2 * 0.2f);
            p2 += lk * att2[jj];
        }
        float p = p2.x + p2.y;
        p += __shfl_xor(p, 1, 64);
        p += __shfl_xor(p, 2, 64);
        p += __shfl_xor(p, 4, 64);
        p += __shfl_xor(p, 8, 64);
        p = ok ? p : -1e30f;
        p5[i] = p;
        amax = fmaxf(amax, p);
    }
    float den = 0.f;
    f32x2 o2[4] = {{0.f,0.f},{0.f,0.f},{0.f,0.f},{0.f,0.f}};
    #pragma unroll
    for (int i = 0; i < 5; ++i) {
        float ex = __expf(p5[i] - amax);
        den += ex;
        f32x2 e2 = {ex, ex};
        #pragma unroll
        for (int jj = 0; jj < 4; ++jj) o2[jj] += e2 * vf2[i][jj];
    }
    float inv = 1.0f / den;
    f32x2 inv2 = {inv, inv};

    u16* xrow = x + (size_t)row * FF + c;
    bf16x8 xv = *(const bf16x8*)xrow;
    const u32* xvu = (const u32*)&xv;
    f32x2 y2[4];
    float sum = 0.f, sq = 0.f;
    #pragma unroll
    for (int jj = 0; jj < 4; ++jj) {
        f32x2 bo2 = ((const f32x2*)(bo + c))[jj];
        y2[jj] = o2[jj] * inv2 + bo2 + bfp2f(xvu[jj]);
        sum += y2[jj].x + y2[jj].y;
        sq  += y2[jj].x * y2[jj].x + y2[jj].y * y2[jj].y;
    }
    sum += __shfl_xor(sum, 1, 64); sq += __shfl_xor(sq, 1, 64);
    sum += __shfl_xor(sum, 2, 64); sq += __shfl_xor(sq, 2, 64);
    sum += __shfl_xor(sum, 4, 64); sq += __shfl_xor(sq, 4, 64);
    sum += __shfl_xor(sum, 8, 64); sq += __shfl_xor(sq, 8, 64);

    __shared__ float ssum[4][4], ssq[4][4];
    if (t == 0) { ssum[h][s] = sum; ssq[h][s] = sq; }
    __syncthreads();
    float tot = ssum[0][s] + ssum[1][s] + ssum[2][s] + ssum[3][s];
    float tq  = ssq[0][s] + ssq[1][s] + ssq[2][s] + ssq[3][s];
    float mu = tot * (1.0f / 512.0f);
    float var = tq * (1.0f / 512.0f) - mu * mu;
    float rs = rsqrtf(var + 1e-5f);

    bf16x8 ov;
    #pragma unroll
    for (int jj = 0; jj < 4; ++jj) {
        f32x2 g2  = ((const f32x2*)(g + c))[jj];
        f32x2 bt2 = ((const f32x2*)(bta + c))[jj];
        f32x2 mu2 = {mu, mu};
        f32x2 rs2 = {rs, rs};
        f32x2 z2 = (y2[jj] - mu2) * rs2 * g2 + bt2;
        float z0 = z2.x, z1 = z2.y;
        if (apply_gelu) { z0 = gelu_f(z0); z1 = gelu_f(z1); }
        ov[jj * 2]     = (short)f2b(z0);
        ov[jj * 2 + 1] = (short)f2b(z1);
    }
    *(bf16x8*)xrow = ov;
}

// ---------- pooling: mean & max over 80 nodes ----------
__global__ __launch_bounds__(512)
void pool_kernel(const u16* __restrict__ x, u16* __restrict__ pooled)
{
    int b = blockIdx.x;
    int f = threadIdx.x;
    const u16* base = x + (size_t)b * NN * FF + f;
    float s = 0.f, mx = -1e30f;
    #pragma unroll 4
    for (int n = 0; n < NN; ++n) {
        float v = b2f(base[(size_t)n * FF]);
        s += v; mx = fmaxf(mx, v);
    }
    pooled[(size_t)b * 1024 + f]       = f2b(s * (1.0f / 80.0f));
    pooled[(size_t)b * 1024 + 512 + f] = f2b(mx);
}

// ---------- output head ----------
__global__ __launch_bounds__(128)
void out_head(const u16* __restrict__ pooled, const float* __restrict__ W,
              const float* __restrict__ bia, const float* __restrict__ g,
              const float* __restrict__ bt, float* __restrict__ out)
{
    int b = blockIdx.x;
    int j = threadIdx.x;
    __shared__ float prow[1024];
    for (int i = j; i < 1024; i += 128) prow[i] = b2f(pooled[(size_t)b * 1024 + i]);
    __syncthreads();
    float acc = 0.f;
    #pragma unroll 8
    for (int k = 0; k < 1024; ++k) acc += prow[k] * W[k * 128 + j];
    acc += bia[j];
    float s = acc, q = acc * acc;
    #pragma unroll
    for (int st = 32; st; st >>= 1) { s += __shfl_xor(s, st, 64); q += __shfl_xor(q, st, 64); }
    __shared__ float ps[2], pq[2];
    int w = j >> 6;
    if ((j & 63) == 0) { ps[w] = s; pq[w] = q; }
    __syncthreads();
    float tot = ps[0] + ps[1], tq = pq[0] + pq[1];
    float mu = tot * (1.0f / 128.0f);
    float var = tq * (1.0f / 128.0f) - mu * mu;
    float rs = rsqrtf(var + 1e-5f);
    float z = (acc - mu) * rs * g[j] + bt[j];
    out[(size_t)b * 128 + j] = gelu_f(z);
}

// ---------- launch ----------
extern "C" void kernel_launch(void* const* d_in, const int* in_sizes, int n_in,
                              void* d_out, int out_size, void* d_ws, size_t ws_size,
                              hipStream_t stream)
{
    (void)in_sizes; (void)n_in; (void)out_size; (void)ws_size;
    const float* mirna    = (const float*)d_in[0];
    const float* target   = (const float*)d_in[1];
    const float* nte      = (const float*)d_in[2];
    const float* eemb     = (const float*)d_in[3];
    const float* in_W     = (const float*)d_in[4];
    const float* in_b     = (const float*)d_in[5];
    const float* in_ln_g  = (const float*)d_in[6];
    const float* in_ln_b  = (const float*)d_in[7];
    const float* gat_Wl   = (const float*)d_in[8];
    const float* gat_bl   = (const float*)d_in[9];
    const float* gat_Wr   = (const float*)d_in[10];
    const float* gat_br   = (const float*)d_in[11];
    const float* gat_We   = (const float*)d_in[12];
    const float* gat_att  = (const float*)d_in[13];
    const float* gat_bo   = (const float*)d_in[14];
    const float* ln_g     = (const float*)d_in[15];
    const float* ln_b     = (const float*)d_in[16];
    const float* out_W    = (const float*)d_in[17];
    const float* out_b    = (const float*)d_in[18];
    const float* out_ln_g = (const float*)d_in[19];
    const float* out_ln_b = (const float*)d_in[20];

    char* ws = (char*)d_ws;
    u16*   x      = (u16*)(ws + X_OFF);
    u16*   xlr    = (u16*)(ws + XLR_OFF);
    u16*   xin    = xlr;
    u16*   pooled = xlr;
    u16*   inWt   = (u16*)(ws + INWT_OFF);
    u16*   Wlrt   = (u16*)(ws + WLRT_OFF);
    float* biaslr = (float*)(ws + BIAS_OFF);
    float* eereal = (float*)(ws + EER_OFF);
    float* eeself = (float*)(ws + EES_OFF);

    prep_misc<<<4944, 256, 0, stream>>>(in_W, gat_Wl, gat_bl, gat_Wr, gat_br, gat_We, eemb,
                                        inWt, Wlrt, biaslr, eereal, eeself);
    prep_xin<<<ROWS / 4, 256, 0, stream>>>(mirna, target, nte, xin);

    // input projection: 320 row-blocks x 2 col-blocks = 640 (div by 8)
    gemm_nt_bias<512, 256><<<(ROWS / 256) * 2, 1024, 0, stream>>>(xin, inWt, in_b, x);
    ln_gelu_rows<<<ROWS / 4, 256, 0, stream>>>(x, in_ln_g, in_ln_b);

    for (int l = 0; l < 2; ++l) {
        // layer GEMM: 320 x 4 = 1280 blocks (div by 8)
        gemm_nt_bias<1024, 512><<<(ROWS / 256) * 4, 1024, 0, stream>>>(
            x, Wlrt + (size_t)l * 524288, biaslr + l * 1024, xlr);
        gat_layer<<<ROWS / 4, 256, 0, stream>>>(x, xlr,
                                                gat_att + l * 512,
                                                eereal + l * 1024,
                                                eeself + (size_t)l * 40960,
                                                gat_bo + l * 512,
                                                ln_g + l * 512, ln_b + l * 512,
                                                (l == 0) ? 1 : 0);
    }

    pool_kernel<<<NB, 512, 0, stream>>>(x, pooled);
    out_head<<<NB, 128, 0, stream>>>(pooled, out_W, out_b, out_ln_g, out_ln_b, (float*)d_out);
}

// Round 15
// 549.619 us; speedup vs baseline: 1.0314x; 1.0314x over previous
//
#include <hip/hip_runtime.h>
#include <hip/hip_bf16.h>

typedef unsigned short u16;
typedef unsigned int u32;
typedef __attribute__((ext_vector_type(8))) short bf16x8;
typedef __attribute__((ext_vector_type(4))) float f32x4;

#define NB   1024
#define LMI  30
#define LTG  50
#define NN   80
#define ROWS (NB*NN)      // 81920
#define FF   512
#define HH   4
#define CC   128

// ---------- helpers ----------
__device__ __forceinline__ u16 f2b(float f) {
    u32 u = __float_as_uint(f);
    u32 r = (u + 0x7FFFu + ((u >> 16) & 1u)) >> 16;
    return (u16)r;
}
__device__ __forceinline__ float b2f(u16 h) {
    return __uint_as_float(((u32)h) << 16);
}
__device__ __forceinline__ float gelu_f(float v) {
    return 0.5f * v * (1.0f + erff(v * 0.70710678118654752440f));
}
// async global->LDS, 16B per lane; LDS dest is wave-uniform base + lane*16
__device__ __forceinline__ void gload_lds16(const void* g, void* l) {
    __builtin_amdgcn_global_load_lds(
        (__attribute__((address_space(1))) void*)(uintptr_t)g,
        (__attribute__((address_space(3))) void*)(uintptr_t)l,
        16, 0, 0);
}

// ---------- workspace layout (bytes) ----------
#define X_OFF     0ULL
#define XLR_OFF   83886080ULL                 // x: 81920*512*2
#define INWT_OFF  251658240ULL                // xlr: 81920*1024*2
#define WLRT_OFF  (INWT_OFF + 262144ULL)
#define BIAS_OFF  (WLRT_OFF + 2097152ULL)
#define EER_OFF   (BIAS_OFF + 8192ULL)
#define EES_OFF   (EER_OFF + 8192ULL)
// total ws needed = EES_OFF + 327680 = 254,361,600 B

// ---------- prep: weight transpose/convert + edge tables ----------
__global__ __launch_bounds__(256)
void prep_misc(const float* __restrict__ in_W, const float* __restrict__ gat_Wl,
               const float* __restrict__ gat_bl, const float* __restrict__ gat_Wr,
               const float* __restrict__ gat_br, const float* __restrict__ gat_We,
               const float* __restrict__ eemb,
               u16* __restrict__ inWt, u16* __restrict__ Wlrt,
               float* __restrict__ biaslr, float* __restrict__ eereal,
               float* __restrict__ eeself)
{
    int idx = blockIdx.x * 256 + threadIdx.x;
    if (idx < 131072) {
        int n = idx >> 8, k = idx & 255;
        inWt[idx] = f2b(in_W[k * 512 + n]);
        return;
    }
    idx -= 131072;
    if (idx < 1048576) {
        int l = idx >> 19; int r = idx & 524287; int n = r >> 9, k = r & 511;
        float v = (n < 512) ? gat_Wl[(size_t)l * 262144 + (size_t)k * 512 + n]
                            : gat_Wr[(size_t)l * 262144 + (size_t)k * 512 + (n - 512)];
        Wlrt[idx] = f2b(v);
        return;
    }
    idx -= 1048576;
    if (idx < 2048) {
        int l = idx >> 10, n = idx & 1023;
        biaslr[idx] = (n < 512) ? gat_bl[l * 512 + n] : gat_br[l * 512 + (n - 512)];
        return;
    }
    idx -= 2048;
    if (idx < 2048) {
        int l = idx >> 10; int r = idx & 1023; int t = r >> 9, f = r & 511;
        int et = t ? 2 : 0;
        float v = 0.f;
        #pragma unroll
        for (int h = 0; h < 4; ++h)
            v += eemb[et * 4 + h] * gat_We[l * 2048 + h * 512 + f];
        eereal[idx] = v;
        return;
    }
    idx -= 2048;
    if (idx < 81920) {
        int l = idx / 40960; int r = idx % 40960; int n = r >> 9, f = r & 511;
        int LL = (n < LMI) ? LMI : LTG;
        int p  = (n < LMI) ? n : (n - LMI);
        float c1 = (float)((p >= 1) + (p <= LL - 2));
        float c2 = (float)((p >= 2) + (p <= LL - 3));
        float ic = 1.0f / (c1 + c2);
        float v = 0.f;
        #pragma unroll
        for (int h = 0; h < 4; ++h) {
            float attr = (c1 * eemb[0 * 4 + h] + c2 * eemb[2 * 4 + h]) * ic;
            v += attr * gat_We[l * 2048 + h * 512 + f];
        }
        eeself[idx] = v;
        return;
    }
}

// ---------- prep: build xin (input + node-type emb) in bf16, 4 nodes/block ----------
__global__ __launch_bounds__(256)
void prep_xin(const float* __restrict__ mirna, const float* __restrict__ target,
              const float* __restrict__ nte, u16* __restrict__ xin)
{
    int bid = blockIdx.x * 4 + (threadIdx.x >> 6);   // b*80+n
    int b = bid / NN, n = bid % NN;
    int t = threadIdx.x & 63;
    const float* src; const float* tv;
    if (n < LMI) { src = mirna + ((size_t)b * LMI + n) * 256; tv = nte; }
    else         { src = target + ((size_t)b * LTG + (n - LMI)) * 256; tv = nte + 256; }
    float4 v = *(const float4*)(src + t * 4);
    float4 e = *(const float4*)(tv + t * 4);
    u32 p0 = (u32)f2b(v.x + e.x) | ((u32)f2b(v.y + e.y) << 16);
    u32 p1 = (u32)f2b(v.z + e.z) | ((u32)f2b(v.w + e.w) << 16);
    *(uint2*)(xin + (size_t)bid * 256 + t * 4) = make_uint2(p0, p1);
}

// ---------- GEMM (r12-proven best: 110us layer): 256x256 tile, 16 waves,
// wave tile 64x64, BK=64, 2 LDS buffers, STAGE-first + one vmcnt(0)+barrier
// at step end, XOR kslot staging (0 conflicts), XCD swizzle, 8B epilogue ----
template<int N, int K>
__global__ __launch_bounds__(1024, 1)
void gemm_nt_bias(const u16* __restrict__ A, const u16* __restrict__ Bt,
                  const float* __restrict__ bias, u16* __restrict__ Cout)
{
    __shared__ __align__(16) u16 sm[2][4][8192];   // 128 KiB
    const int tid = threadIdx.x;
    const int w = tid >> 6, l = tid & 63;   // w: 0..15
    constexpr int ncb = N / 256;
    constexpr int nsteps = K >> 6;

    const int per = gridDim.x >> 3;
    const int nid = (blockIdx.x & 7) * per + (blockIdx.x >> 3);
    const int row0 = (nid / ncb) * 256;
    const int col0 = (nid % ncb) * 256;
    const int wr = w >> 2, wc = w & 3;      // wave tile rows [wr*64,+64), cols [wc*64,+64)

    const int srow = l >> 2;
    const int kperm = ((l & 3) ^ ((l >> 3) & 3)) * 8;
    const u16* Ag = A  + (size_t)(row0 + w * 16 + srow) * K + kperm;
    const u16* Bg = Bt + (size_t)(col0 + w * 16 + srow) * K + kperm;

#define STAGE(buf, t) do { int _ko = (t) << 6;                  \
        gload_lds16(Ag + _ko,      &sm[buf][0][w * 512]);       \
        gload_lds16(Ag + _ko + 32, &sm[buf][1][w * 512]);       \
        gload_lds16(Bg + _ko,      &sm[buf][2][w * 512]);       \
        gload_lds16(Bg + _ko + 32, &sm[buf][3][w * 512]);       \
    } while (0)

    f32x4 acc[4][4];
    #pragma unroll
    for (int r = 0; r < 4; ++r)
        #pragma unroll
        for (int f = 0; f < 4; ++f)
            acc[r][f] = (f32x4){0.f, 0.f, 0.f, 0.f};

    const int ll = l & 15, lh = l >> 4;
    const int aoff = ll * 32 + ((lh ^ ((ll >> 1) & 3)) * 8);
    const int aB = wr * 4 * 512 + aoff;
    const int bB = wc * 4 * 512 + aoff;

    STAGE(0, 0);
    asm volatile("s_waitcnt vmcnt(0)" ::: "memory");
    __builtin_amdgcn_s_barrier();

    #pragma unroll
    for (int t = 0; t < nsteps; ++t) {
        const int cur = t & 1;
        if (t + 1 < nsteps) STAGE(cur ^ 1, t + 1);

        #pragma unroll
        for (int kh = 0; kh < 2; ++kh) {
            bf16x8 af[4], bfr[4];
            #pragma unroll
            for (int ar = 0; ar < 4; ++ar)
                af[ar] = *(const bf16x8*)&sm[cur][kh][aB + ar * 512];
            #pragma unroll
            for (int fc = 0; fc < 4; ++fc)
                bfr[fc] = *(const bf16x8*)&sm[cur][2 + kh][bB + fc * 512];
            __builtin_amdgcn_s_setprio(1);
            #pragma unroll
            for (int ar = 0; ar < 4; ++ar)
                #pragma unroll
                for (int fc = 0; fc < 4; ++fc)
                    acc[ar][fc] = __builtin_amdgcn_mfma_f32_16x16x32_bf16(
                        bfr[fc], af[ar], acc[ar][fc], 0, 0, 0);
            __builtin_amdgcn_s_setprio(0);
        }

        if (t + 1 < nsteps) {
            asm volatile("s_waitcnt vmcnt(0)" ::: "memory");
            __builtin_amdgcn_s_barrier();
        }
    }
#undef STAGE

    #pragma unroll
    for (int ar = 0; ar < 4; ++ar) {
        int grow = row0 + wr * 64 + ar * 16 + ll;
        #pragma unroll
        for (int fc = 0; fc < 4; ++fc) {
            int n0 = col0 + wc * 64 + fc * 16 + lh * 4;
            float4 bv = *(const float4*)(bias + n0);
            u32 lo = (u32)f2b(acc[ar][fc][0] + bv.x) | ((u32)f2b(acc[ar][fc][1] + bv.y) << 16);
            u32 hi = (u32)f2b(acc[ar][fc][2] + bv.z) | ((u32)f2b(acc[ar][fc][3] + bv.w) << 16);
            *(uint2*)&Cout[(size_t)grow * N + n0] = make_uint2(lo, hi);
        }
    }
}

// ---------- row LN + gelu: 4 rows/block, wave per row, 8 ch/lane ----------
__global__ __launch_bounds__(256)
void ln_gelu_rows(u16* __restrict__ x, const float* __restrict__ g, const float* __restrict__ b)
{
    int w = threadIdx.x >> 6, l = threadIdx.x & 63;
    size_t row = (size_t)blockIdx.x * 4 + w;
    u16* rp = x + row * FF + l * 8;
    bf16x8 v = *(const bf16x8*)rp;
    float y[8]; float s = 0.f, q = 0.f;
    #pragma unroll
    for (int j = 0; j < 8; ++j) { y[j] = b2f((u16)v[j]); s += y[j]; q += y[j] * y[j]; }
    #pragma unroll
    for (int st = 32; st; st >>= 1) { s += __shfl_xor(s, st, 64); q += __shfl_xor(q, st, 64); }
    float mu = s * (1.0f / 512.0f);
    float var = q * (1.0f / 512.0f) - mu * mu;
    float rs = rsqrtf(var + 1e-5f);
    float4 g0 = *(const float4*)(g + l * 8), g1 = *(const float4*)(g + l * 8 + 4);
    float4 b0 = *(const float4*)(b + l * 8), b1 = *(const float4*)(b + l * 8 + 4);
    float gv[8] = {g0.x, g0.y, g0.z, g0.w, g1.x, g1.y, g1.z, g1.w};
    float bv[8] = {b0.x, b0.y, b0.z, b0.w, b1.x, b1.y, b1.z, b1.w};
    bf16x8 o;
    #pragma unroll
    for (int j = 0; j < 8; ++j) {
        float z = (y[j] - mu) * rs * gv[j] + bv[j];
        o[j] = (short)f2b(gelu_f(z));
    }
    *(bf16x8*)rp = o;
}

// ---------- fused GAT layer: 8 nodes/block (512 thr), wave covers 4 nodes
// for one head; XCD-chunked block swizzle for xlr neighbor-row L2 locality.
// Math identical to r11/r12 (session-best) version.
__global__ __launch_bounds__(512)
void gat_layer(u16* __restrict__ x, const u16* __restrict__ xlr,
               const float* __restrict__ att, const float* __restrict__ eereal,
               const float* __restrict__ eeself, const float* __restrict__ bo,
               const float* __restrict__ g, const float* __restrict__ bta,
               int apply_gelu)
{
    int tid = threadIdx.x;
    int w = tid >> 6, l = tid & 63;
    int h = w & 3, ng = w >> 2;          // head, node-group (0/1)
    int s = (l >> 4) + ng * 4;           // node 0..7 within block
    int t = l & 15;

    // XCD-chunked swizzle (grid divisible by 8): contiguous node range per XCD
    const int per = gridDim.x >> 3;
    const int nid = (blockIdx.x & 7) * per + (blockIdx.x >> 3);
    int row = nid * 8 + s;               // global node row
    int n = row % NN;
    int lo = (n < LMI) ? 0 : LMI;
    int hi = (n < LMI) ? (LMI - 1) : (NN - 1);
    int c = h * CC + t * 8;              // 8 channels [c, c+8)

    bf16x8 xrv = *(const bf16x8*)(xlr + (size_t)row * 1024 + 512 + c);
    float xr[8], atv[8];
    #pragma unroll
    for (int j = 0; j < 8; ++j) xr[j] = b2f((u16)xrv[j]);
    {
        float4 a0 = *(const float4*)(att + c), a1 = *(const float4*)(att + c + 4);
        atv[0]=a0.x; atv[1]=a0.y; atv[2]=a0.z; atv[3]=a0.w;
        atv[4]=a1.x; atv[5]=a1.y; atv[6]=a1.z; atv[7]=a1.w;
    }

    float xre[3][8];
    {
        const float* e0p = eereal + c;
        const float* e1p = eereal + 512 + c;
        const float* e2p = eeself + (size_t)n * 512 + c;
        float4 a0 = *(const float4*)e0p, a1 = *(const float4*)(e0p + 4);
        float4 b0 = *(const float4*)e1p, b1 = *(const float4*)(e1p + 4);
        float4 c0 = *(const float4*)e2p, c1 = *(const float4*)(e2p + 4);
        float e0a[8] = {a0.x,a0.y,a0.z,a0.w,a1.x,a1.y,a1.z,a1.w};
        float e1a[8] = {b0.x,b0.y,b0.z,b0.w,b1.x,b1.y,b1.z,b1.w};
        float e2a[8] = {c0.x,c0.y,c0.z,c0.w,c1.x,c1.y,c1.z,c1.w};
        #pragma unroll
        for (int j = 0; j < 8; ++j) {
            xre[0][j] = xr[j] + e0a[j];
            xre[1][j] = xr[j] + e1a[j];
            xre[2][j] = xr[j] + e2a[j];
        }
    }

    float vf[5][8];
    float p5[5];
    float amax = -1e30f;
    #pragma unroll
    for (int i = 0; i < 5; ++i) {
        int d = i - 2;
        int src = n + d;
        bool ok = (src >= lo) && (src <= hi);
        int dd = ok ? d : 0;
        bf16x8 vv = *(const bf16x8*)(xlr + (size_t)(row + dd) * 1024 + c);
        const int sel = (i == 2) ? 2 : ((i == 1 || i == 3) ? 0 : 1);
        float p = 0.f;
        #pragma unroll
        for (int j = 0; j < 8; ++j) {
            float v = b2f((u16)vv[j]);
            vf[i][j] = v;
            float m = v + xre[sel][j];
            m = fmaxf(m, m * 0.2f);
            p += m * atv[j];
        }
        p += __shfl_xor(p, 1, 64);
        p += __shfl_xor(p, 2, 64);
        p += __shfl_xor(p, 4, 64);
        p += __shfl_xor(p, 8, 64);
        p = ok ? p : -1e30f;
        p5[i] = p;
        amax = fmaxf(amax, p);
    }
    float den = 0.f;
    float o[8] = {0.f,0.f,0.f,0.f,0.f,0.f,0.f,0.f};
    #pragma unroll
    for (int i = 0; i < 5; ++i) {
        float ex = __expf(p5[i] - amax);
        den += ex;
        #pragma unroll
        for (int j = 0; j < 8; ++j) o[j] += ex * vf[i][j];
    }
    float inv = 1.0f / den;

    u16* xrow = x + (size_t)row * FF + c;
    bf16x8 xv = *(const bf16x8*)xrow;
    float bov[8];
    {
        float4 b0 = *(const float4*)(bo + c), b1 = *(const float4*)(bo + c + 4);
        bov[0]=b0.x; bov[1]=b0.y; bov[2]=b0.z; bov[3]=b0.w;
        bov[4]=b1.x; bov[5]=b1.y; bov[6]=b1.z; bov[7]=b1.w;
    }
    float y[8]; float sum = 0.f, sq = 0.f;
    #pragma unroll
    for (int j = 0; j < 8; ++j) {
        y[j] = o[j] * inv + bov[j] + b2f((u16)xv[j]);
        sum += y[j]; sq += y[j] * y[j];
    }
    sum += __shfl_xor(sum, 1, 64); sq += __shfl_xor(sq, 1, 64);
    sum += __shfl_xor(sum, 2, 64); sq += __shfl_xor(sq, 2, 64);
    sum += __shfl_xor(sum, 4, 64); sq += __shfl_xor(sq, 4, 64);
    sum += __shfl_xor(sum, 8, 64); sq += __shfl_xor(sq, 8, 64);

    __shared__ float ssum[4][8], ssq[4][8];
    if (t == 0) { ssum[h][s] = sum; ssq[h][s] = sq; }
    __syncthreads();
    float tot = ssum[0][s] + ssum[1][s] + ssum[2][s] + ssum[3][s];
    float tq  = ssq[0][s] + ssq[1][s] + ssq[2][s] + ssq[3][s];
    float mu = tot * (1.0f / 512.0f);
    float var = tq * (1.0f / 512.0f) - mu * mu;
    float rs = rsqrtf(var + 1e-5f);

    float gv[8], btv[8];
    {
        float4 g0 = *(const float4*)(g + c), g1 = *(const float4*)(g + c + 4);
        float4 t0 = *(const float4*)(bta + c), t1 = *(const float4*)(bta + c + 4);
        gv[0]=g0.x; gv[1]=g0.y; gv[2]=g0.z; gv[3]=g0.w;
        gv[4]=g1.x; gv[5]=g1.y; gv[6]=g1.z; gv[7]=g1.w;
        btv[0]=t0.x; btv[1]=t0.y; btv[2]=t0.z; btv[3]=t0.w;
        btv[4]=t1.x; btv[5]=t1.y; btv[6]=t1.z; btv[7]=t1.w;
    }
    bf16x8 ov;
    #pragma unroll
    for (int j = 0; j < 8; ++j) {
        float z = (y[j] - mu) * rs * gv[j] + btv[j];
        if (apply_gelu) z = gelu_f(z);
        ov[j] = (short)f2b(z);
    }
    *(bf16x8*)xrow = ov;
}

// ---------- pooling: mean & max over 80 nodes ----------
__global__ __launch_bounds__(512)
void pool_kernel(const u16* __restrict__ x, u16* __restrict__ pooled)
{
    int b = blockIdx.x;
    int f = threadIdx.x;
    const u16* base = x + (size_t)b * NN * FF + f;
    float s = 0.f, mx = -1e30f;
    #pragma unroll 4
    for (int n = 0; n < NN; ++n) {
        float v = b2f(base[(size_t)n * FF]);
        s += v; mx = fmaxf(mx, v);
    }
    pooled[(size_t)b * 1024 + f]       = f2b(s * (1.0f / 80.0f));
    pooled[(size_t)b * 1024 + 512 + f] = f2b(mx);
}

// ---------- output head ----------
__global__ __launch_bounds__(128)
void out_head(const u16* __restrict__ pooled, const float* __restrict__ W,
              const float* __restrict__ bia, const float* __restrict__ g,
              const float* __restrict__ bt, float* __restrict__ out)
{
    int b = blockIdx.x;
    int j = threadIdx.x;
    __shared__ float prow[1024];
    for (int i = j; i < 1024; i += 128) prow[i] = b2f(pooled[(size_t)b * 1024 + i]);
    __syncthreads();
    float acc = 0.f;
    #pragma unroll 8
    for (int k = 0; k < 1024; ++k) acc += prow[k] * W[k * 128 + j];
    acc += bia[j];
    float s = acc, q = acc * acc;
    #pragma unroll
    for (int st = 32; st; st >>= 1) { s += __shfl_xor(s, st, 64); q += __shfl_xor(q, st, 64); }
    __shared__ float ps[2], pq[2];
    int w = j >> 6;
    if ((j & 63) == 0) { ps[w] = s; pq[w] = q; }
    __syncthreads();
    float tot = ps[0] + ps[1], tq = pq[0] + pq[1];
    float mu = tot * (1.0f / 128.0f);
    float var = tq * (1.0f / 128.0f) - mu * mu;
    float rs = rsqrtf(var + 1e-5f);
    float z = (acc - mu) * rs * g[j] + bt[j];
    out[(size_t)b * 128 + j] = gelu_f(z);
}

// ---------- launch ----------
extern "C" void kernel_launch(void* const* d_in, const int* in_sizes, int n_in,
                              void* d_out, int out_size, void* d_ws, size_t ws_size,
                              hipStream_t stream)
{
    (void)in_sizes; (void)n_in; (void)out_size; (void)ws_size;
    const float* mirna    = (const float*)d_in[0];
    const float* target   = (const float*)d_in[1];
    const float* nte      = (const float*)d_in[2];
    const float* eemb     = (const float*)d_in[3];
    const float* in_W     = (const float*)d_in[4];
    const float* in_b     = (const float*)d_in[5];
    const float* in_ln_g  = (const float*)d_in[6];
    const float* in_ln_b  = (const float*)d_in[7];
    const float* gat_Wl   = (const float*)d_in[8];
    const float* gat_bl   = (const float*)d_in[9];
    const float* gat_Wr   = (const float*)d_in[10];
    const float* gat_br   = (const float*)d_in[11];
    const float* gat_We   = (const float*)d_in[12];
    const float* gat_att  = (const float*)d_in[13];
    const float* gat_bo   = (const float*)d_in[14];
    const float* ln_g     = (const float*)d_in[15];
    const float* ln_b     = (const float*)d_in[16];
    const float* out_W    = (const float*)d_in[17];
    const float* out_b    = (const float*)d_in[18];
    const float* out_ln_g = (const float*)d_in[19];
    const float* out_ln_b = (const float*)d_in[20];

    char* ws = (char*)d_ws;
    u16*   x      = (u16*)(ws + X_OFF);
    u16*   xlr    = (u16*)(ws + XLR_OFF);
    u16*   xin    = xlr;
    u16*   pooled = xlr;
    u16*   inWt   = (u16*)(ws + INWT_OFF);
    u16*   Wlrt   = (u16*)(ws + WLRT_OFF);
    float* biaslr = (float*)(ws + BIAS_OFF);
    float* eereal = (float*)(ws + EER_OFF);
    float* eeself = (float*)(ws + EES_OFF);

    prep_misc<<<4944, 256, 0, stream>>>(in_W, gat_Wl, gat_bl, gat_Wr, gat_br, gat_We, eemb,
                                        inWt, Wlrt, biaslr, eereal, eeself);
    prep_xin<<<ROWS / 4, 256, 0, stream>>>(mirna, target, nte, xin);

    // input projection: 320 row-blocks x 2 col-blocks = 640 (div by 8)
    gemm_nt_bias<512, 256><<<(ROWS / 256) * 2, 1024, 0, stream>>>(xin, inWt, in_b, x);
    ln_gelu_rows<<<ROWS / 4, 256, 0, stream>>>(x, in_ln_g, in_ln_b);

    for (int l = 0; l < 2; ++l) {
        // layer GEMM: 320 x 4 = 1280 blocks (div by 8)
        gemm_nt_bias<1024, 512><<<(ROWS / 256) * 4, 1024, 0, stream>>>(
            x, Wlrt + (size_t)l * 524288, biaslr + l * 1024, xlr);
        // gat: 10240 blocks (div by 8), 8 nodes per 512-thread block
        gat_layer<<<ROWS / 8, 512, 0, stream>>>(x, xlr,
                                                gat_att + l * 512,
                                                eereal + l * 1024,
                                                eeself + (size_t)l * 40960,
                                                gat_bo + l * 512,
                                                ln_g + l * 512, ln_b + l * 512,
                                                (l == 0) ? 1 : 0);
    }

    pool_kernel<<<NB, 512, 0, stream>>>(x, pooled);
    out_head<<<NB, 128, 0, stream>>>(pooled, out_W, out_b, out_ln_g, out_ln_b, (float*)d_out);
}

// Round 16
// 544.330 us; speedup vs baseline: 1.0414x; 1.0097x over previous
//
#include <hip/hip_runtime.h>
#include <hip/hip_bf16.h>

typedef unsigned short u16;
typedef unsigned int u32;
typedef __attribute__((ext_vector_type(8))) short bf16x8;
typedef __attribute__((ext_vector_type(4))) float f32x4;

#define NB   1024
#define LMI  30
#define LTG  50
#define NN   80
#define ROWS (NB*NN)      // 81920
#define FF   512
#define HH   4
#define CC   128

// ---------- helpers ----------
__device__ __forceinline__ u16 f2b(float f) {
    u32 u = __float_as_uint(f);
    u32 r = (u + 0x7FFFu + ((u >> 16) & 1u)) >> 16;
    return (u16)r;
}
__device__ __forceinline__ float b2f(u16 h) {
    return __uint_as_float(((u32)h) << 16);
}
__device__ __forceinline__ float gelu_f(float v) {
    return 0.5f * v * (1.0f + erff(v * 0.70710678118654752440f));
}
// async global->LDS, 16B per lane; LDS dest is wave-uniform base + lane*16
__device__ __forceinline__ void gload_lds16(const void* g, void* l) {
    __builtin_amdgcn_global_load_lds(
        (__attribute__((address_space(1))) void*)(uintptr_t)g,
        (__attribute__((address_space(3))) void*)(uintptr_t)l,
        16, 0, 0);
}

// ---------- workspace layout (bytes) ----------
#define X_OFF     0ULL
#define XLR_OFF   83886080ULL                 // x: 81920*512*2
#define INWT_OFF  251658240ULL                // xlr: 81920*1024*2
#define WLRT_OFF  (INWT_OFF + 262144ULL)
#define BIAS_OFF  (WLRT_OFF + 2097152ULL)
#define EER_OFF   (BIAS_OFF + 8192ULL)
#define EES_OFF   (EER_OFF + 8192ULL)
// total ws needed = EES_OFF + 327680 = 254,361,600 B

// ---------- prep: weight transpose/convert + edge tables ----------
__global__ __launch_bounds__(256)
void prep_misc(const float* __restrict__ in_W, const float* __restrict__ gat_Wl,
               const float* __restrict__ gat_bl, const float* __restrict__ gat_Wr,
               const float* __restrict__ gat_br, const float* __restrict__ gat_We,
               const float* __restrict__ eemb,
               u16* __restrict__ inWt, u16* __restrict__ Wlrt,
               float* __restrict__ biaslr, float* __restrict__ eereal,
               float* __restrict__ eeself)
{
    int idx = blockIdx.x * 256 + threadIdx.x;
    if (idx < 131072) {
        int n = idx >> 8, k = idx & 255;
        inWt[idx] = f2b(in_W[k * 512 + n]);
        return;
    }
    idx -= 131072;
    if (idx < 1048576) {
        int l = idx >> 19; int r = idx & 524287; int n = r >> 9, k = r & 511;
        float v = (n < 512) ? gat_Wl[(size_t)l * 262144 + (size_t)k * 512 + n]
                            : gat_Wr[(size_t)l * 262144 + (size_t)k * 512 + (n - 512)];
        Wlrt[idx] = f2b(v);
        return;
    }
    idx -= 1048576;
    if (idx < 2048) {
        int l = idx >> 10, n = idx & 1023;
        biaslr[idx] = (n < 512) ? gat_bl[l * 512 + n] : gat_br[l * 512 + (n - 512)];
        return;
    }
    idx -= 2048;
    if (idx < 2048) {
        int l = idx >> 10; int r = idx & 1023; int t = r >> 9, f = r & 511;
        int et = t ? 2 : 0;
        float v = 0.f;
        #pragma unroll
        for (int h = 0; h < 4; ++h)
            v += eemb[et * 4 + h] * gat_We[l * 2048 + h * 512 + f];
        eereal[idx] = v;
        return;
    }
    idx -= 2048;
    if (idx < 81920) {
        int l = idx / 40960; int r = idx % 40960; int n = r >> 9, f = r & 511;
        int LL = (n < LMI) ? LMI : LTG;
        int p  = (n < LMI) ? n : (n - LMI);
        float c1 = (float)((p >= 1) + (p <= LL - 2));
        float c2 = (float)((p >= 2) + (p <= LL - 3));
        float ic = 1.0f / (c1 + c2);
        float v = 0.f;
        #pragma unroll
        for (int h = 0; h < 4; ++h) {
            float attr = (c1 * eemb[0 * 4 + h] + c2 * eemb[2 * 4 + h]) * ic;
            v += attr * gat_We[l * 2048 + h * 512 + f];
        }
        eeself[idx] = v;
        return;
    }
}

// ---------- prep: build xin (input + node-type emb) in bf16, 4 nodes/block ----------
__global__ __launch_bounds__(256)
void prep_xin(const float* __restrict__ mirna, const float* __restrict__ target,
              const float* __restrict__ nte, u16* __restrict__ xin)
{
    int bid = blockIdx.x * 4 + (threadIdx.x >> 6);   // b*80+n
    int b = bid / NN, n = bid % NN;
    int t = threadIdx.x & 63;
    const float* src; const float* tv;
    if (n < LMI) { src = mirna + ((size_t)b * LMI + n) * 256; tv = nte; }
    else         { src = target + ((size_t)b * LTG + (n - LMI)) * 256; tv = nte + 256; }
    float4 v = *(const float4*)(src + t * 4);
    float4 e = *(const float4*)(tv + t * 4);
    u32 p0 = (u32)f2b(v.x + e.x) | ((u32)f2b(v.y + e.y) << 16);
    u32 p1 = (u32)f2b(v.z + e.z) | ((u32)f2b(v.w + e.w) << 16);
    *(uint2*)(xin + (size_t)bid * 256 + t * 4) = make_uint2(p0, p1);
}

// ---------- GEMM (r12-proven best: 110us layer): 256x256 tile, 16 waves,
// wave tile 64x64, BK=64, 2 LDS buffers, STAGE-first + one vmcnt(0)+barrier
// at step end, XOR kslot staging (0 conflicts), XCD swizzle, 8B epilogue ----
template<int N, int K>
__global__ __launch_bounds__(1024, 1)
void gemm_nt_bias(const u16* __restrict__ A, const u16* __restrict__ Bt,
                  const float* __restrict__ bias, u16* __restrict__ Cout)
{
    __shared__ __align__(16) u16 sm[2][4][8192];   // 128 KiB
    const int tid = threadIdx.x;
    const int w = tid >> 6, l = tid & 63;   // w: 0..15
    constexpr int ncb = N / 256;
    constexpr int nsteps = K >> 6;

    const int per = gridDim.x >> 3;
    const int nid = (blockIdx.x & 7) * per + (blockIdx.x >> 3);
    const int row0 = (nid / ncb) * 256;
    const int col0 = (nid % ncb) * 256;
    const int wr = w >> 2, wc = w & 3;      // wave tile rows [wr*64,+64), cols [wc*64,+64)

    const int srow = l >> 2;
    const int kperm = ((l & 3) ^ ((l >> 3) & 3)) * 8;
    const u16* Ag = A  + (size_t)(row0 + w * 16 + srow) * K + kperm;
    const u16* Bg = Bt + (size_t)(col0 + w * 16 + srow) * K + kperm;

#define STAGE(buf, t) do { int _ko = (t) << 6;                  \
        gload_lds16(Ag + _ko,      &sm[buf][0][w * 512]);       \
        gload_lds16(Ag + _ko + 32, &sm[buf][1][w * 512]);       \
        gload_lds16(Bg + _ko,      &sm[buf][2][w * 512]);       \
        gload_lds16(Bg + _ko + 32, &sm[buf][3][w * 512]);       \
    } while (0)

    f32x4 acc[4][4];
    #pragma unroll
    for (int r = 0; r < 4; ++r)
        #pragma unroll
        for (int f = 0; f < 4; ++f)
            acc[r][f] = (f32x4){0.f, 0.f, 0.f, 0.f};

    const int ll = l & 15, lh = l >> 4;
    const int aoff = ll * 32 + ((lh ^ ((ll >> 1) & 3)) * 8);
    const int aB = wr * 4 * 512 + aoff;
    const int bB = wc * 4 * 512 + aoff;

    STAGE(0, 0);
    asm volatile("s_waitcnt vmcnt(0)" ::: "memory");
    __builtin_amdgcn_s_barrier();

    #pragma unroll
    for (int t = 0; t < nsteps; ++t) {
        const int cur = t & 1;
        if (t + 1 < nsteps) STAGE(cur ^ 1, t + 1);

        #pragma unroll
        for (int kh = 0; kh < 2; ++kh) {
            bf16x8 af[4], bfr[4];
            #pragma unroll
            for (int ar = 0; ar < 4; ++ar)
                af[ar] = *(const bf16x8*)&sm[cur][kh][aB + ar * 512];
            #pragma unroll
            for (int fc = 0; fc < 4; ++fc)
                bfr[fc] = *(const bf16x8*)&sm[cur][2 + kh][bB + fc * 512];
            __builtin_amdgcn_s_setprio(1);
            #pragma unroll
            for (int ar = 0; ar < 4; ++ar)
                #pragma unroll
                for (int fc = 0; fc < 4; ++fc)
                    acc[ar][fc] = __builtin_amdgcn_mfma_f32_16x16x32_bf16(
                        bfr[fc], af[ar], acc[ar][fc], 0, 0, 0);
            __builtin_amdgcn_s_setprio(0);
        }

        if (t + 1 < nsteps) {
            asm volatile("s_waitcnt vmcnt(0)" ::: "memory");
            __builtin_amdgcn_s_barrier();
        }
    }
#undef STAGE

    #pragma unroll
    for (int ar = 0; ar < 4; ++ar) {
        int grow = row0 + wr * 64 + ar * 16 + ll;
        #pragma unroll
        for (int fc = 0; fc < 4; ++fc) {
            int n0 = col0 + wc * 64 + fc * 16 + lh * 4;
            float4 bv = *(const float4*)(bias + n0);
            u32 lo = (u32)f2b(acc[ar][fc][0] + bv.x) | ((u32)f2b(acc[ar][fc][1] + bv.y) << 16);
            u32 hi = (u32)f2b(acc[ar][fc][2] + bv.z) | ((u32)f2b(acc[ar][fc][3] + bv.w) << 16);
            *(uint2*)&Cout[(size_t)grow * N + n0] = make_uint2(lo, hi);
        }
    }
}

// ---------- row LN + gelu: 4 rows/block, wave per row, 8 ch/lane ----------
__global__ __launch_bounds__(256)
void ln_gelu_rows(u16* __restrict__ x, const float* __restrict__ g, const float* __restrict__ b)
{
    int w = threadIdx.x >> 6, l = threadIdx.x & 63;
    size_t row = (size_t)blockIdx.x * 4 + w;
    u16* rp = x + row * FF + l * 8;
    bf16x8 v = *(const bf16x8*)rp;
    float y[8]; float s = 0.f, q = 0.f;
    #pragma unroll
    for (int j = 0; j < 8; ++j) { y[j] = b2f((u16)v[j]); s += y[j]; q += y[j] * y[j]; }
    #pragma unroll
    for (int st = 32; st; st >>= 1) { s += __shfl_xor(s, st, 64); q += __shfl_xor(q, st, 64); }
    float mu = s * (1.0f / 512.0f);
    float var = q * (1.0f / 512.0f) - mu * mu;
    float rs = rsqrtf(var + 1e-5f);
    float4 g0 = *(const float4*)(g + l * 8), g1 = *(const float4*)(g + l * 8 + 4);
    float4 b0 = *(const float4*)(b + l * 8), b1 = *(const float4*)(b + l * 8 + 4);
    float gv[8] = {g0.x, g0.y, g0.z, g0.w, g1.x, g1.y, g1.z, g1.w};
    float bv[8] = {b0.x, b0.y, b0.z, b0.w, b1.x, b1.y, b1.z, b1.w};
    bf16x8 o;
    #pragma unroll
    for (int j = 0; j < 8; ++j) {
        float z = (y[j] - mu) * rs * gv[j] + bv[j];
        o[j] = (short)f2b(gelu_f(z));
    }
    *(bf16x8*)rp = o;
}

// ---------- fused GAT layer: 4 nodes/block, wave=head, 16 lanes/node, 8 ch/lane ----------
// VALU-trimmed (r11): edge values converted once, xr+ee precomputed per type.
__global__ __launch_bounds__(256)
void gat_layer(u16* __restrict__ x, const u16* __restrict__ xlr,
               const float* __restrict__ att, const float* __restrict__ eereal,
               const float* __restrict__ eeself, const float* __restrict__ bo,
               const float* __restrict__ g, const float* __restrict__ bta,
               int apply_gelu)
{
    int tid = threadIdx.x;
    int h = tid >> 6, l = tid & 63;
    int s = l >> 4, t = l & 15;
    int row = blockIdx.x * 4 + s;        // global node row
    int n = row % NN;
    int lo = (n < LMI) ? 0 : LMI;
    int hi = (n < LMI) ? (LMI - 1) : (NN - 1);
    int c = h * CC + t * 8;              // 8 channels [c, c+8)

    bf16x8 xrv = *(const bf16x8*)(xlr + (size_t)row * 1024 + 512 + c);
    float xr[8], atv[8];
    #pragma unroll
    for (int j = 0; j < 8; ++j) xr[j] = b2f((u16)xrv[j]);
    {
        float4 a0 = *(const float4*)(att + c), a1 = *(const float4*)(att + c + 4);
        atv[0]=a0.x; atv[1]=a0.y; atv[2]=a0.z; atv[3]=a0.w;
        atv[4]=a1.x; atv[5]=a1.y; atv[6]=a1.z; atv[7]=a1.w;
    }

    float xre[3][8];
    {
        const float* e0p = eereal + c;
        const float* e1p = eereal + 512 + c;
        const float* e2p = eeself + (size_t)n * 512 + c;
        float4 a0 = *(const float4*)e0p, a1 = *(const float4*)(e0p + 4);
        float4 b0 = *(const float4*)e1p, b1 = *(const float4*)(e1p + 4);
        float4 c0 = *(const float4*)e2p, c1 = *(const float4*)(e2p + 4);
        float e0a[8] = {a0.x,a0.y,a0.z,a0.w,a1.x,a1.y,a1.z,a1.w};
        float e1a[8] = {b0.x,b0.y,b0.z,b0.w,b1.x,b1.y,b1.z,b1.w};
        float e2a[8] = {c0.x,c0.y,c0.z,c0.w,c1.x,c1.y,c1.z,c1.w};
        #pragma unroll
        for (int j = 0; j < 8; ++j) {
            xre[0][j] = xr[j] + e0a[j];
            xre[1][j] = xr[j] + e1a[j];
            xre[2][j] = xr[j] + e2a[j];
        }
    }

    float vf[5][8];
    float p5[5];
    float amax = -1e30f;
    #pragma unroll
    for (int i = 0; i < 5; ++i) {
        int d = i - 2;
        int src = n + d;
        bool ok = (src >= lo) && (src <= hi);
        int dd = ok ? d : 0;
        bf16x8 vv = *(const bf16x8*)(xlr + (size_t)(row + dd) * 1024 + c);
        const int sel = (i == 2) ? 2 : ((i == 1 || i == 3) ? 0 : 1);
        float p = 0.f;
        #pragma unroll
        for (int j = 0; j < 8; ++j) {
            float v = b2f((u16)vv[j]);
            vf[i][j] = v;
            float m = v + xre[sel][j];
            m = fmaxf(m, m * 0.2f);
            p += m * atv[j];
        }
        p += __shfl_xor(p, 1, 64);
        p += __shfl_xor(p, 2, 64);
        p += __shfl_xor(p, 4, 64);
        p += __shfl_xor(p, 8, 64);
        p = ok ? p : -1e30f;
        p5[i] = p;
        amax = fmaxf(amax, p);
    }
    float den = 0.f;
    float o[8] = {0.f,0.f,0.f,0.f,0.f,0.f,0.f,0.f};
    #pragma unroll
    for (int i = 0; i < 5; ++i) {
        float ex = __expf(p5[i] - amax);
        den += ex;
        #pragma unroll
        for (int j = 0; j < 8; ++j) o[j] += ex * vf[i][j];
    }
    float inv = 1.0f / den;

    u16* xrow = x + (size_t)row * FF + c;
    bf16x8 xv = *(const bf16x8*)xrow;
    float bov[8];
    {
        float4 b0 = *(const float4*)(bo + c), b1 = *(const float4*)(bo + c + 4);
        bov[0]=b0.x; bov[1]=b0.y; bov[2]=b0.z; bov[3]=b0.w;
        bov[4]=b1.x; bov[5]=b1.y; bov[6]=b1.z; bov[7]=b1.w;
    }
    float y[8]; float sum = 0.f, sq = 0.f;
    #pragma unroll
    for (int j = 0; j < 8; ++j) {
        y[j] = o[j] * inv + bov[j] + b2f((u16)xv[j]);
        sum += y[j]; sq += y[j] * y[j];
    }
    sum += __shfl_xor(sum, 1, 64); sq += __shfl_xor(sq, 1, 64);
    sum += __shfl_xor(sum, 2, 64); sq += __shfl_xor(sq, 2, 64);
    sum += __shfl_xor(sum, 4, 64); sq += __shfl_xor(sq, 4, 64);
    sum += __shfl_xor(sum, 8, 64); sq += __shfl_xor(sq, 8, 64);

    __shared__ float ssum[4][4], ssq[4][4];
    if (t == 0) { ssum[h][s] = sum; ssq[h][s] = sq; }
    __syncthreads();
    float tot = ssum[0][s] + ssum[1][s] + ssum[2][s] + ssum[3][s];
    float tq  = ssq[0][s] + ssq[1][s] + ssq[2][s] + ssq[3][s];
    float mu = tot * (1.0f / 512.0f);
    float var = tq * (1.0f / 512.0f) - mu * mu;
    float rs = rsqrtf(var + 1e-5f);

    float gv[8], btv[8];
    {
        float4 g0 = *(const float4*)(g + c), g1 = *(const float4*)(g + c + 4);
        float4 t0 = *(const float4*)(bta + c), t1 = *(const float4*)(bta + c + 4);
        gv[0]=g0.x; gv[1]=g0.y; gv[2]=g0.z; gv[3]=g0.w;
        gv[4]=g1.x; gv[5]=g1.y; gv[6]=g1.z; gv[7]=g1.w;
        btv[0]=t0.x; btv[1]=t0.y; btv[2]=t0.z; btv[3]=t0.w;
        btv[4]=t1.x; btv[5]=t1.y; btv[6]=t1.z; btv[7]=t1.w;
    }
    bf16x8 ov;
    #pragma unroll
    for (int j = 0; j < 8; ++j) {
        float z = (y[j] - mu) * rs * gv[j] + btv[j];
        if (apply_gelu) z = gelu_f(z);
        ov[j] = (short)f2b(z);
    }
    *(bf16x8*)xrow = ov;
}

// ---------- pooling: mean & max over 80 nodes ----------
__global__ __launch_bounds__(512)
void pool_kernel(const u16* __restrict__ x, u16* __restrict__ pooled)
{
    int b = blockIdx.x;
    int f = threadIdx.x;
    const u16* base = x + (size_t)b * NN * FF + f;
    float s = 0.f, mx = -1e30f;
    #pragma unroll 4
    for (int n = 0; n < NN; ++n) {
        float v = b2f(base[(size_t)n * FF]);
        s += v; mx = fmaxf(mx, v);
    }
    pooled[(size_t)b * 1024 + f]       = f2b(s * (1.0f / 80.0f));
    pooled[(size_t)b * 1024 + 512 + f] = f2b(mx);
}

// ---------- output head ----------
__global__ __launch_bounds__(128)
void out_head(const u16* __restrict__ pooled, const float* __restrict__ W,
              const float* __restrict__ bia, const float* __restrict__ g,
              const float* __restrict__ bt, float* __restrict__ out)
{
    int b = blockIdx.x;
    int j = threadIdx.x;
    __shared__ float prow[1024];
    for (int i = j; i < 1024; i += 128) prow[i] = b2f(pooled[(size_t)b * 1024 + i]);
    __syncthreads();
    float acc = 0.f;
    #pragma unroll 8
    for (int k = 0; k < 1024; ++k) acc += prow[k] * W[k * 128 + j];
    acc += bia[j];
    float s = acc, q = acc * acc;
    #pragma unroll
    for (int st = 32; st; st >>= 1) { s += __shfl_xor(s, st, 64); q += __shfl_xor(q, st, 64); }
    __shared__ float ps[2], pq[2];
    int w = j >> 6;
    if ((j & 63) == 0) { ps[w] = s; pq[w] = q; }
    __syncthreads();
    float tot = ps[0] + ps[1], tq = pq[0] + pq[1];
    float mu = tot * (1.0f / 128.0f);
    float var = tq * (1.0f / 128.0f) - mu * mu;
    float rs = rsqrtf(var + 1e-5f);
    float z = (acc - mu) * rs * g[j] + bt[j];
    out[(size_t)b * 128 + j] = gelu_f(z);
}

// ---------- launch ----------
extern "C" void kernel_launch(void* const* d_in, const int* in_sizes, int n_in,
                              void* d_out, int out_size, void* d_ws, size_t ws_size,
                              hipStream_t stream)
{
    (void)in_sizes; (void)n_in; (void)out_size; (void)ws_size;
    const float* mirna    = (const float*)d_in[0];
    const float* target   = (const float*)d_in[1];
    const float* nte      = (const float*)d_in[2];
    const float* eemb     = (const float*)d_in[3];
    const float* in_W     = (const float*)d_in[4];
    const float* in_b     = (const float*)d_in[5];
    const float* in_ln_g  = (const float*)d_in[6];
    const float* in_ln_b  = (const float*)d_in[7];
    const float* gat_Wl   = (const float*)d_in[8];
    const float* gat_bl   = (const float*)d_in[9];
    const float* gat_Wr   = (const float*)d_in[10];
    const float* gat_br   = (const float*)d_in[11];
    const float* gat_We   = (const float*)d_in[12];
    const float* gat_att  = (const float*)d_in[13];
    const float* gat_bo   = (const float*)d_in[14];
    const float* ln_g     = (const float*)d_in[15];
    const float* ln_b     = (const float*)d_in[16];
    const float* out_W    = (const float*)d_in[17];
    const float* out_b    = (const float*)d_in[18];
    const float* out_ln_g = (const float*)d_in[19];
    const float* out_ln_b = (const float*)d_in[20];

    char* ws = (char*)d_ws;
    u16*   x      = (u16*)(ws + X_OFF);
    u16*   xlr    = (u16*)(ws + XLR_OFF);
    u16*   xin    = xlr;
    u16*   pooled = xlr;
    u16*   inWt   = (u16*)(ws + INWT_OFF);
    u16*   Wlrt   = (u16*)(ws + WLRT_OFF);
    float* biaslr = (float*)(ws + BIAS_OFF);
    float* eereal = (float*)(ws + EER_OFF);
    float* eeself = (float*)(ws + EES_OFF);

    prep_misc<<<4944, 256, 0, stream>>>(in_W, gat_Wl, gat_bl, gat_Wr, gat_br, gat_We, eemb,
                                        inWt, Wlrt, biaslr, eereal, eeself);
    prep_xin<<<ROWS / 4, 256, 0, stream>>>(mirna, target, nte, xin);

    // input projection: 320 row-blocks x 2 col-blocks = 640 (div by 8)
    gemm_nt_bias<512, 256><<<(ROWS / 256) * 2, 1024, 0, stream>>>(xin, inWt, in_b, x);
    ln_gelu_rows<<<ROWS / 4, 256, 0, stream>>>(x, in_ln_g, in_ln_b);

    for (int l = 0; l < 2; ++l) {
        // layer GEMM: 320 x 4 = 1280 blocks (div by 8)
        gemm_nt_bias<1024, 512><<<(ROWS / 256) * 4, 1024, 0, stream>>>(
            x, Wlrt + (size_t)l * 524288, biaslr + l * 1024, xlr);
        gat_layer<<<ROWS / 4, 256, 0, stream>>>(x, xlr,
                                                gat_att + l * 512,
                                                eereal + l * 1024,
                                                eeself + (size_t)l * 40960,
                                                gat_bo + l * 512,
                                                ln_g + l * 512, ln_b + l * 512,
                                                (l == 0) ? 1 : 0);
    }

    pool_kernel<<<NB, 512, 0, stream>>>(x, pooled);
    out_head<<<NB, 128, 0, stream>>>(pooled, out_W, out_b, out_ln_g, out_ln_b, (float*)d_out);
}